// Round 1
// baseline (8422.581 us; speedup 1.0000x reference)
//
#include <hip/hip_runtime.h>

// MovieNet: 6 proj GEMMs(+tanh+dot epilogue) -> 21 softmax -> enc xg (K=6 GEMM)
// -> enc LSTM (persistent) -> ctx -> dec xg GEMM -> dec LSTM (persistent) -> MLP.
// R4: LSTM rebalanced 64 WGs -> 16 WGs x 256 thr (32 hidden units each).
//     - per-WG h slice = 64 B = exactly one line per batch: full-line publishes,
//       no partial-line sc1 RMW (was 4x write amplification, WRITE_SIZE 132MB).
//     - flags = 16 dwords = ONE line; 64 polling waves instead of 128 on 4 lines.
//     - enc xg precomputed (xgenc_k): both LSTMs identical K=512, xg prefetched
//       per step (independent of h), no per-step enc_in staging stragglers.
//     - outbuf reverts to normal L2 write-back stores (one WG per line now).

#define B_ 32
#define T_ 512
#define H_ 512
#define M_ (B_*T_)   // 16384
#define NWG 16       // persistent LSTM workgroups (each owns 32 hidden units)
#define KS 16        // K=512 / 32 per MFMA

typedef __attribute__((ext_vector_type(8))) short bf16x8;
typedef __attribute__((ext_vector_type(4))) float f32x4;

__device__ inline unsigned short f2bf(float f){
  unsigned int u = __builtin_bit_cast(unsigned int, f);
  u += 0x7fffu + ((u>>16)&1u);      // round-to-nearest-even
  return (unsigned short)(u>>16);
}
__device__ inline float bf2f(unsigned short s){
  unsigned int u = ((unsigned int)s)<<16;
  return __builtin_bit_cast(float, u);
}
__device__ inline float tanh_f(float x){
  float ax = fabsf(x);
  if (ax > 12.f) return (x>0.f)?1.f:-1.f;
  float e = __expf(2.f*ax);
  float t = (e-1.f)/(e+1.f);
  return (x>=0.f)? t : -t;
}
__device__ inline float sigm(float x){ return 1.f/(1.f+__expf(-x)); }

// Device-scope (MALL coherence point) raw memory ops. Plain VMEM, fully
// pipelined, bypass L1/L2 via sc1 — no atomic RMW path.
__device__ inline void st_u32_sc1(void* p, unsigned int v){
  asm volatile("global_store_dword %0, %1, off sc1" :: "v"(p), "v"(v) : "memory");
}
__device__ inline void st_u64_sc1(void* p, unsigned long long v){
  asm volatile("global_store_dwordx2 %0, %1, off sc1" :: "v"(p), "v"(v) : "memory");
}
__device__ inline bf16x8 ld_b128_sc1(const void* p){
  bf16x8 r;
  asm volatile("global_load_dwordx4 %0, %1, off sc1" : "=v"(r) : "v"(p));
  return r;
}

// ---------------------------------------------------------------------------
// Tiled bf16 GEMM, 128x128 tile, BK=32, 256 thr (4 waves, 2x2 of 64x64).
// MODE 0: A=fp32 features, epilogue tanh(acc+bias) then dot with w1/w2/w3,
//         atomicAdd row partials into s1/s2/s3 (t_x never materialized).
// MODE 1: A=bf16, epilogue acc+bias -> bf16 store.
// MODE 2: A=bf16, epilogue relu(acc+bias) -> bf16 store.
template<int MODE>
__global__ __launch_bounds__(256)
void gemm_k(const void* __restrict__ Ap, const float* __restrict__ Bw,
            const float* __restrict__ bias, int K,
            float* __restrict__ s1, float* __restrict__ s2, float* __restrict__ s3,
            const float* __restrict__ w1, const float* __restrict__ w2, const float* __restrict__ w3,
            unsigned short* __restrict__ outp, int ldout)
{
  __shared__ short As[128*40];   // +8 pad elems per row: conflict-free b128 reads
  __shared__ short Bs[128*40];
  const int tid = threadIdx.x;
  const int cb = blockIdx.x, rb = blockIdx.y;
  const int lane = tid & 63, wv = tid >> 6;
  const int vm = wv & 1, vn = wv >> 1;
  const int r = tid >> 1;
  const int c0 = (tid & 1) << 4;

  f32x4 acc[4][4];
  const f32x4 zz = {0.f,0.f,0.f,0.f};
  #pragma unroll
  for (int i=0;i<4;i++)
    #pragma unroll
    for (int j=0;j<4;j++) acc[i][j] = zz;

  union { short s[16]; bf16x8 v[2]; } tmpu;

  for (int kb = 0; kb < K; kb += 32){
    if (MODE == 0){
      const float* A = (const float*)Ap + (size_t)(rb*128 + r)*K + kb + c0;
      #pragma unroll
      for (int q=0;q<4;q++){
        float4 vv = ((const float4*)A)[q];
        tmpu.s[q*4+0]=(short)f2bf(vv.x); tmpu.s[q*4+1]=(short)f2bf(vv.y);
        tmpu.s[q*4+2]=(short)f2bf(vv.z); tmpu.s[q*4+3]=(short)f2bf(vv.w);
      }
      *(bf16x8*)&As[r*40 + c0]   = tmpu.v[0];
      *(bf16x8*)&As[r*40 + c0+8] = tmpu.v[1];
    } else {
      const unsigned short* A = (const unsigned short*)Ap + (size_t)(rb*128 + r)*K + kb + c0;
      uint4 u0 = ((const uint4*)A)[0];
      uint4 u1 = ((const uint4*)A)[1];
      *(uint4*)&As[r*40 + c0]   = u0;
      *(uint4*)&As[r*40 + c0+8] = u1;
    }
    {
      const float* Bp = Bw + (size_t)(cb*128 + r)*K + kb + c0;
      #pragma unroll
      for (int q=0;q<4;q++){
        float4 vv = ((const float4*)Bp)[q];
        tmpu.s[q*4+0]=(short)f2bf(vv.x); tmpu.s[q*4+1]=(short)f2bf(vv.y);
        tmpu.s[q*4+2]=(short)f2bf(vv.z); tmpu.s[q*4+3]=(short)f2bf(vv.w);
      }
      *(bf16x8*)&Bs[r*40 + c0]   = tmpu.v[0];
      *(bf16x8*)&Bs[r*40 + c0+8] = tmpu.v[1];
    }
    __syncthreads();
    bf16x8 af[4], bfr[4];
    const int fo = ((lane>>4)<<3);
    #pragma unroll
    for (int i=0;i<4;i++) af[i]  = *(const bf16x8*)&As[(vm*64 + i*16 + (lane&15))*40 + fo];
    #pragma unroll
    for (int i=0;i<4;i++) bfr[i] = *(const bf16x8*)&Bs[(vn*64 + i*16 + (lane&15))*40 + fo];
    #pragma unroll
    for (int mt=0;mt<4;mt++)
      #pragma unroll
      for (int nt=0;nt<4;nt++)
        acc[mt][nt] = __builtin_amdgcn_mfma_f32_16x16x32_bf16(af[mt], bfr[nt], acc[mt][nt], 0,0,0);
    __syncthreads();
  }

  const int rowbase = rb*128 + vm*64;
  const int colbase = cb*128 + vn*64;
  if (MODE == 0){
    float bv[4], w1v[4], w2v[4], w3v[4];
    #pragma unroll
    for (int nt=0;nt<4;nt++){
      int c = colbase + nt*16 + (lane&15);
      bv[nt]=bias[c]; w1v[nt]=w1[c]; w2v[nt]=w2[c]; w3v[nt]=w3[c];
    }
    #pragma unroll
    for (int mt=0;mt<4;mt++){
      #pragma unroll
      for (int rr=0;rr<4;rr++){
        float d1=0.f,d2=0.f,d3=0.f;
        #pragma unroll
        for (int nt=0;nt<4;nt++){
          float tv = tanh_f(acc[mt][nt][rr] + bv[nt]);
          d1 = fmaf(tv, w1v[nt], d1);
          d2 = fmaf(tv, w2v[nt], d2);
          d3 = fmaf(tv, w3v[nt], d3);
        }
        #pragma unroll
        for (int m=1;m<16;m<<=1){
          d1 += __shfl_xor(d1, m);
          d2 += __shfl_xor(d2, m);
          d3 += __shfl_xor(d3, m);
        }
        if ((lane & 15) == 0){
          int row = rowbase + mt*16 + ((lane>>4)<<2) + rr;
          atomicAdd(&s1[row], d1);
          atomicAdd(&s2[row], d2);
          atomicAdd(&s3[row], d3);
        }
      }
    }
  } else {
    #pragma unroll
    for (int mt=0;mt<4;mt++){
      #pragma unroll
      for (int nt=0;nt<4;nt++){
        int c = colbase + nt*16 + (lane&15);
        float bb = bias[c];
        #pragma unroll
        for (int rr=0;rr<4;rr++){
          int row = rowbase + mt*16 + ((lane>>4)<<2) + rr;
          float vv = acc[mt][nt][rr] + bb;
          if (MODE == 2) vv = fmaxf(vv, 0.f);
          outp[(size_t)row*ldout + c] = f2bf(vv);
        }
      }
    }
  }
}

// ---------------------------------------------------------------------------
// 21 softmaxes over T per batch. Scalar biases omitted (softmax shift-invariant).
__global__ __launch_bounds__(256)
void softmax_k(const float* __restrict__ sacc, float* __restrict__ sm)
{
  const int u = blockIdx.x % 21, b = blockIdx.x / 21;
  const int tid = threadIdx.x;
  __shared__ float red[4], red2[4];
  float v0, v1;
  if (u < 15){
    const int pa[15] = {0,0,0,0,0,1,1,1,1,2,2,2,3,3,4};
    const int pb[15] = {2,1,3,4,5,2,3,4,5,3,4,5,4,5,5};
    const float* A  = sacc + (size_t)(pa[u]*3+0)*M_ + b*T_;
    const float* Bq = sacc + (size_t)(pb[u]*3+1)*M_ + b*T_;
    v0 = A[tid] + Bq[tid]; v1 = A[tid+256] + Bq[tid+256];
  } else {
    const float* A = sacc + (size_t)((u-15)*3+2)*M_ + b*T_;
    v0 = A[tid]; v1 = A[tid+256];
  }
  float mx = fmaxf(v0,v1);
  #pragma unroll
  for (int d=1;d<64;d<<=1) mx = fmaxf(mx, __shfl_xor(mx,d));
  if ((tid&63)==0) red[tid>>6]=mx;
  __syncthreads();
  mx = fmaxf(fmaxf(red[0],red[1]),fmaxf(red[2],red[3]));
  float e0 = __expf(v0-mx), e1 = __expf(v1-mx);
  float s = e0+e1;
  #pragma unroll
  for (int d=1;d<64;d<<=1) s += __shfl_xor(s,d);
  if ((tid&63)==0) red2[tid>>6]=s;
  __syncthreads();
  s = red2[0]+red2[1]+red2[2]+red2[3];
  float inv = 1.f/s;
  float* o = sm + (size_t)u*M_ + b*T_;
  o[tid] = e0*inv; o[tid+256] = e1*inv;
}

// ---------------------------------------------------------------------------
// enc xg precompute: xg[row, R] = enc_b[R] + sum_{k<6} smu[k][row] * Wih[R,k].
// Wih transposed into LDS (Ws[k][R]) for conflict-free reads; threads own
// R = tid + i*256 so stores coalesce (64 lanes -> 128 B contiguous).
__global__ __launch_bounds__(256)
void xgenc_k(const float* __restrict__ smu, const float* __restrict__ Wih,
             const float* __restrict__ bvec, unsigned short* __restrict__ xgo)
{
  __shared__ float Ws[6][2048];
  __shared__ float bs[2048];
  const int tid = threadIdx.x;
  for (int i = tid; i < 6*2048; i += 256){
    int R = i / 6, k = i - R*6;
    Ws[k][R] = Wih[i];
  }
  for (int i = tid; i < 2048; i += 256) bs[i] = bvec[i];
  __syncthreads();
  const int r0 = blockIdx.x * 64;
  for (int r = r0; r < r0 + 64; r++){
    float s0 = smu[0*M_ + r], s1 = smu[1*M_ + r], s2 = smu[2*M_ + r];
    float s3 = smu[3*M_ + r], s4 = smu[4*M_ + r], s5 = smu[5*M_ + r];
    unsigned short* orow = xgo + (size_t)r*2048;
    #pragma unroll
    for (int i = 0; i < 8; i++){
      int R = tid + i*256;
      float a = bs[R];
      a = fmaf(s0, Ws[0][R], a); a = fmaf(s1, Ws[1][R], a);
      a = fmaf(s2, Ws[2][R], a); a = fmaf(s3, Ws[3][R], a);
      a = fmaf(s4, Ws[4][R], a); a = fmaf(s5, Ws[5][R], a);
      orow[R] = f2bf(a);
    }
  }
}

// ---------------------------------------------------------------------------
// Seed dec LSTM h0 into hbd buf0. Normal stores: kernel-boundary release
// flushes to MALL before lstm_k's sc1 reads.
__global__ __launch_bounds__(256)
void init2_k(const float* __restrict__ dh0, unsigned short* __restrict__ hbd)
{
  int gid = blockIdx.x*256 + threadIdx.x;  // 0..16383
  int bb = gid >> 9, j = gid & 511;
  hbd[bb*512 + j] = f2bf(dh0[j]);
}

// ---------------------------------------------------------------------------
// Persistent LSTM. 16 WGs x 256 thr (4 waves). WG w owns hidden [w*32, w*32+32)
// = 128 gate rows of W_hh resident in VGPR fragments (128 KB bf16 / WG).
// Gates for all 32 batches via MFMA: A = h (K=512), B = W_hh rows.
// xg (= x-projection + bias, both LSTMs) precomputed; prefetched per step
// before the poll (independent of h -> latency hidden).
// h exchanged via double-buffered global hbuf with per-WG step flags:
//   - per-WG slice per batch = 32 bf16 = 64 B = ONE line (full-line publishes)
//   - flags = 16 dwords = ONE line
// All cross-WG traffic: plain sc1 (device-scope) loads/stores via inline asm.
// Ordering: all threads s_waitcnt vmcnt(0) -> __syncthreads -> tid0 flag store.
// Invariant: flag=t implies that WG finished READING buf[(t-1)&1], so buffer
// reuse at t+1 is race-free.
__global__ __launch_bounds__(256, 1)
void lstm_k(const float* __restrict__ Whh, const unsigned short* __restrict__ xg,
            const float* __restrict__ c0v,
            unsigned short* hbuf, int* flags, unsigned short* __restrict__ outbuf)
{
  const int w = blockIdx.x, tid = threadIdx.x;
  const int lane = tid & 63, v = tid >> 6;   // wave 0..3

  // Weight fragments: wave v covers WG gate-rows rWG = v*32 + nt*16 + (lane&15),
  // rWG -> (gate = rWG&3, hidden_off = rWG>>2), R = gate*512 + w*32 + hidden_off.
  bf16x8 bfrag[2][KS];
  {
    const int n = lane & 15;
    const int kq0 = (lane>>4)<<3;
    #pragma unroll
    for (int nt=0; nt<2; nt++){
      const int rWG = v*32 + nt*16 + n;
      const int R = (rWG & 3)*512 + w*32 + (rWG >> 2);
      const float* Wr = Whh + (size_t)R*512 + kq0;
      for (int ks=0; ks<KS; ks++){
        union { short s[8]; bf16x8 vv; } bu;
        #pragma unroll
        for (int j=0;j<8;j++) bu.s[j] = (short)f2bf(Wr[ks*32 + j]);
        bfrag[nt][ks] = bu.vv;
      }
    }
  }
  const int b = tid & 31, u = tid >> 5;      // batch, hidden-quad index
  const int j0 = w*32 + u*4;                 // this thread's 4 hidden units
  float cc[4];
  #pragma unroll
  for (int e=0;e<4;e++) cc[e] = c0v ? c0v[j0+e] : 0.f;

  __shared__ float gl[128*33];
  const int m = lane & 15;
  const int kq = (lane>>4)<<3;

  for (int t = 1; t <= 512; t++){
    // prefetch xg row (independent of h; normal cached loads)
    unsigned long long xq[4];
    {
      const unsigned short* xp = xg + ((size_t)(b*512 + (t-1)))*2048 + j0;
      #pragma unroll
      for (int g=0; g<4; g++) xq[g] = *(const unsigned long long*)(xp + g*512);
    }
    // wait for all WGs to have published step t-1 (ONE flag line)
    {
      const int want = t-1;
      const int* fp = flags + (lane & 15);
      int f;
      do {
        asm volatile("global_load_dword %0, %1, off sc1\n\ts_waitcnt vmcnt(0)"
                     : "=v"(f) : "v"(fp) : "memory");
      } while (!__all(f >= want));
    }
    const unsigned short* hb = hbuf + ((t-1)&1)*(32*512);
    f32x4 acc[2][2];
    const f32x4 zz = {0.f,0.f,0.f,0.f};
    acc[0][0]=zz; acc[0][1]=zz; acc[1][0]=zz; acc[1][1]=zz;
    {
      bf16x8 af0[KS], af1[KS];
      #pragma unroll
      for (int ks=0; ks<KS; ks++){
        af0[ks] = ld_b128_sc1(hb + (size_t)m*512 + ks*32 + kq);
        af1[ks] = ld_b128_sc1(hb + (size_t)(m+16)*512 + ks*32 + kq);
      }
      asm volatile("s_waitcnt vmcnt(0)" ::: "memory");
      __builtin_amdgcn_sched_barrier(0);
      #pragma unroll
      for (int ks=0; ks<KS; ks++){   // register barrier: pin MFMA after waitcnt
        asm volatile("" : "+v"(af0[ks]));
        asm volatile("" : "+v"(af1[ks]));
      }
      #pragma unroll
      for (int ks=0; ks<KS; ks++){
        acc[0][0] = __builtin_amdgcn_mfma_f32_16x16x32_bf16(af0[ks], bfrag[0][ks], acc[0][0], 0,0,0);
        acc[0][1] = __builtin_amdgcn_mfma_f32_16x16x32_bf16(af0[ks], bfrag[1][ks], acc[0][1], 0,0,0);
        acc[1][0] = __builtin_amdgcn_mfma_f32_16x16x32_bf16(af1[ks], bfrag[0][ks], acc[1][0], 0,0,0);
        acc[1][1] = __builtin_amdgcn_mfma_f32_16x16x32_bf16(af1[ks], bfrag[1][ks], acc[1][1], 0,0,0);
      }
    }
    // gate exchange: gl[rWG][batch]
    {
      const int qb = (lane>>4)<<2;
      #pragma unroll
      for (int mt=0; mt<2; mt++)
        #pragma unroll
        for (int nt=0; nt<2; nt++){
          const int col = v*32 + nt*16 + (lane&15);
          #pragma unroll
          for (int rr=0; rr<4; rr++)
            gl[col*33 + mt*16 + qb + rr] = acc[mt][nt][rr];
        }
    }
    __syncthreads();
    unsigned long long hv;
    {
      float hn[4];
      #pragma unroll
      for (int e=0;e<4;e++){
        const int ro = (u*4+e)*4;
        float gi = gl[(ro+0)*33 + b] + bf2f((unsigned short)(xq[0] >> (e*16)));
        float gf = gl[(ro+1)*33 + b] + bf2f((unsigned short)(xq[1] >> (e*16)));
        float gg = gl[(ro+2)*33 + b] + bf2f((unsigned short)(xq[2] >> (e*16)));
        float go = gl[(ro+3)*33 + b] + bf2f((unsigned short)(xq[3] >> (e*16)));
        cc[e] = sigm(gf)*cc[e] + sigm(gi)*tanh_f(gg);
        hn[e] = sigm(go)*tanh_f(cc[e]);
      }
      unsigned int h0 = (unsigned int)f2bf(hn[0]) | ((unsigned int)f2bf(hn[1])<<16);
      unsigned int h1 = (unsigned int)f2bf(hn[2]) | ((unsigned int)f2bf(hn[3])<<16);
      hv = (unsigned long long)h0 | ((unsigned long long)h1<<32);
    }
    unsigned short* hbw = hbuf + (t&1)*(32*512);
    st_u64_sc1(hbw + (size_t)b*512 + j0, hv);
    // outbuf: one WG per 64B line -> normal write-back store, flushed at kernel end
    *(unsigned long long*)(outbuf + ((size_t)(b*512 + (t-1)))*512 + j0) = hv;
    // Drain this thread's stores, then barrier so tid0's flag covers the WG.
    asm volatile("s_waitcnt vmcnt(0)" ::: "memory");
    __syncthreads();
    if (tid == 0) st_u32_sc1(&flags[w], (unsigned int)t);
  }
}

// ---------------------------------------------------------------------------
// ctx[b,t,:] = sum_{i<15, t-i>=0} attn[b,t,i]*enc_out[b,t-i,:], attn via interleave gather.
__global__ __launch_bounds__(256)
void ctx_k(const float* __restrict__ smatt, const unsigned short* __restrict__ enc_out,
           unsigned short* __restrict__ ctx)
{
  const int bt = blockIdx.x;
  const int b = bt >> 9, t = bt & 511;
  __shared__ float a[15];
  const int tid = threadIdx.x;
  if (tid < 15){
    int q = 15*t + tid;
    a[tid] = smatt[(size_t)(q>>9)*M_ + b*T_ + (q&511)];
  }
  __syncthreads();
  const int j0 = tid*2;
  float s0=0.f, s1=0.f;
  for (int i=0;i<15;i++){
    int tau = t - i;
    if (tau < 0) break;
    unsigned int pr = *(const unsigned int*)(enc_out + ((size_t)(b*512+tau))*512 + j0);
    float wv = a[i];
    s0 = fmaf(wv, bf2f((unsigned short)(pr & 0xffff)), s0);
    s1 = fmaf(wv, bf2f((unsigned short)(pr >> 16)), s1);
  }
  unsigned int o = (unsigned int)f2bf(s0) | ((unsigned int)f2bf(s1)<<16);
  *(unsigned int*)(ctx + (size_t)bt*512 + j0) = o;
}

// ---------------------------------------------------------------------------
// out = hid @ W2.T + b2  (N=7 skinny). One wave per row.
__global__ __launch_bounds__(256)
void out_k(const unsigned short* __restrict__ hid, const float* __restrict__ W2,
           const float* __restrict__ b2, float* __restrict__ out)
{
  __shared__ float w2s[7*512];
  const int tid = threadIdx.x;
  for (int i = tid; i < 7*512; i += 256) w2s[i] = W2[i];
  __syncthreads();
  const int wv = tid>>6, lane = tid&63;
  const int mrow = blockIdx.x*4 + wv;
  float hv[8];
  {
    const uint4 uu = *(const uint4*)(hid + (size_t)mrow*512 + lane*8);
    const unsigned int q[4] = {uu.x, uu.y, uu.z, uu.w};
    #pragma unroll
    for (int i=0;i<4;i++){
      hv[i*2]   = bf2f((unsigned short)(q[i] & 0xffff));
      hv[i*2+1] = bf2f((unsigned short)(q[i] >> 16));
    }
  }
  float s[7];
  #pragma unroll
  for (int o=0;o<7;o++){
    float acc = 0.f;
    #pragma unroll
    for (int j=0;j<8;j++) acc = fmaf(hv[j], w2s[o*512 + lane*8 + j], acc);
    #pragma unroll
    for (int d=1; d<64; d<<=1) acc += __shfl_xor(acc, d);
    s[o] = acc;
  }
  if (lane == 0){
    #pragma unroll
    for (int o=0;o<7;o++) out[(size_t)mrow*7 + o] = s[o] + b2[o];
  }
}

// ---------------------------------------------------------------------------
// Workspace layout (needs ~136 MiB)
#define OFF_SACC   0ULL          // 18*16384*4 = 1179648
#define OFF_SM     2097152ULL    // 21*16384*4 = 1376256
#define OFF_FLAGS  3670016ULL    // enc:+0, dec:+256
#define OFF_HBUF_E 4194304ULL    // 2*32*512*2 = 65536
#define OFF_HBUF_D 4325376ULL    // 65536
#define OFF_ENCOUT 5242880ULL    // 16 MiB bf16
#define OFF_CTX    23068672ULL   // 16 MiB bf16
#define OFF_XG     41943040ULL   // 64 MiB bf16 (16384x2048), time-shared enc/dec
#define OFF_DECOUT 109051904ULL  // 16 MiB bf16
#define OFF_HID    125829120ULL  // 16 MiB bf16

extern "C" void kernel_launch(void* const* d_in, const int* in_sizes, int n_in,
                              void* d_out, int out_size, void* d_ws, size_t ws_size,
                              hipStream_t stream)
{
  const float* face  = (const float*)d_in[1];
  const float* audio = (const float*)d_in[2];
  const float* desc  = (const float*)d_in[3];
  const float* sit   = (const float*)d_in[4];
  const float* scene = (const float*)d_in[5];
  const float* text  = (const float*)d_in[6];
  const float* Wt  = (const float*)d_in[8];  const float* bt  = (const float*)d_in[9];
  const float* Wf  = (const float*)d_in[10]; const float* bfc = (const float*)d_in[11];
  const float* Wa  = (const float*)d_in[12]; const float* ba  = (const float*)d_in[13];
  const float* Wsc = (const float*)d_in[14]; const float* bsc = (const float*)d_in[15];
  const float* Wd  = (const float*)d_in[16]; const float* bd  = (const float*)d_in[17];
  const float* Wsi = (const float*)d_in[18]; const float* bsi = (const float*)d_in[19];
  const float* w_att = (const float*)d_in[20];
  const float* w_ut = (const float*)d_in[22];
  const float* w_uf = (const float*)d_in[24];
  const float* w_ua = (const float*)d_in[26];
  const float* enc_Wih = (const float*)d_in[28];
  const float* enc_Whh = (const float*)d_in[29];
  const float* enc_b   = (const float*)d_in[30];
  const float* dec_Wih = (const float*)d_in[31];
  const float* dec_Whh = (const float*)d_in[32];
  const float* dec_b   = (const float*)d_in[33];
  const float* dec_h0  = (const float*)d_in[34];
  const float* dec_c0  = (const float*)d_in[35];
  const float* W1 = (const float*)d_in[36]; const float* b1 = (const float*)d_in[37];
  const float* W2 = (const float*)d_in[38]; const float* b2 = (const float*)d_in[39];
  float* outp = (float*)d_out;

  char* ws = (char*)d_ws;
  float* sacc = (float*)(ws + OFF_SACC);
  float* sm   = (float*)(ws + OFF_SM);
  int* flagsE = (int*)(ws + OFF_FLAGS);
  int* flagsD = (int*)(ws + OFF_FLAGS + 256);
  unsigned short* hbe = (unsigned short*)(ws + OFF_HBUF_E);
  unsigned short* hbd = (unsigned short*)(ws + OFF_HBUF_D);
  unsigned short* enc_out = (unsigned short*)(ws + OFF_ENCOUT);
  unsigned short* ctx = (unsigned short*)(ws + OFF_CTX);
  unsigned short* xg  = (unsigned short*)(ws + OFF_XG);
  unsigned short* dec_out = (unsigned short*)(ws + OFF_DECOUT);
  unsigned short* hid = (unsigned short*)(ws + OFF_HID);
  const float* smu = sm + 15*M_;   // uni softmaxes

  hipMemsetAsync(ws + OFF_SACC, 0, 18*M_*4, stream);
  hipMemsetAsync(ws + OFF_FLAGS, 0, (size_t)(OFF_HBUF_D + 69632 - OFF_FLAGS), stream);

  dim3 blk(256);
  dim3 g1(4,128);
  const float* w1p = w_att; const float* w2p = w_att + 512;
  // feature order: 0=text 1=face 2=audio 3=scene 4=desc 5=sit
  gemm_k<0><<<g1, blk, 0, stream>>>(text,  Wt,  bt,  768,  sacc+0*M_,  sacc+1*M_,  sacc+2*M_,  w1p, w2p, w_ut, nullptr, 0);
  gemm_k<0><<<g1, blk, 0, stream>>>(face,  Wf,  bfc, 512,  sacc+3*M_,  sacc+4*M_,  sacc+5*M_,  w1p, w2p, w_uf, nullptr, 0);
  gemm_k<0><<<g1, blk, 0, stream>>>(audio, Wa,  ba,  128,  sacc+6*M_,  sacc+7*M_,  sacc+8*M_,  w1p, w2p, w_ua, nullptr, 0);
  gemm_k<0><<<g1, blk, 0, stream>>>(scene, Wsc, bsc, 2048, sacc+9*M_,  sacc+10*M_, sacc+11*M_, w1p, w2p, w_ut, nullptr, 0);
  gemm_k<0><<<g1, blk, 0, stream>>>(desc,  Wd,  bd,  768,  sacc+12*M_, sacc+13*M_, sacc+14*M_, w1p, w2p, w_uf, nullptr, 0);
  gemm_k<0><<<g1, blk, 0, stream>>>(sit,   Wsi, bsi, 768,  sacc+15*M_, sacc+16*M_, sacc+17*M_, w1p, w2p, w_ua, nullptr, 0);
  softmax_k<<<dim3(21*32), blk, 0, stream>>>(sacc, sm);
  xgenc_k<<<dim3(256), blk, 0, stream>>>(smu, enc_Wih, enc_b, xg);
  init2_k<<<dim3(64), blk, 0, stream>>>(dec_h0, hbd);
  lstm_k<<<dim3(NWG), dim3(256), 0, stream>>>(enc_Whh, xg, nullptr, hbe, flagsE, enc_out);
  ctx_k<<<dim3(M_), blk, 0, stream>>>(sm, enc_out, ctx);
  gemm_k<1><<<dim3(16,128), blk, 0, stream>>>(ctx, dec_Wih, dec_b, 512,
      nullptr,nullptr,nullptr,nullptr,nullptr,nullptr, xg, 2048);
  lstm_k<<<dim3(NWG), dim3(256), 0, stream>>>(dec_Whh, xg, dec_c0, hbd, flagsD, dec_out);
  gemm_k<2><<<dim3(4,128), blk, 0, stream>>>(dec_out, W1, b1, 512,
      nullptr,nullptr,nullptr,nullptr,nullptr,nullptr, hid, 512);
  out_k<<<dim3(M_/4), blk, 0, stream>>>(hid, W2, b2, outp);
  (void)in_sizes; (void)n_in; (void)out_size; (void)ws_size;
}

// Round 3
// 7984.426 us; speedup vs baseline: 1.0549x; 1.0549x over previous
//
#include <hip/hip_runtime.h>

// MovieNet: 6 proj GEMMs(+tanh+dot epilogue) -> 21 softmax -> enc xg (K=6 GEMM)
// -> enc LSTM (persistent) -> ctx -> dec xg GEMM -> dec LSTM (persistent) -> MLP.
// R6: R5's NaN-sentinel handoff with the recycle-ordering DEADLOCK fixed:
//  - NaN-fill of buf[(t+2)&3] now happens AFTER the step-t poll succeeds.
//    Poll success => all group waves published h_{t-1} => (vmcnt(0) precedes
//    every publish) all waves retired their reads of buf[(t-2)&3] == the fill
//    target. R5 filled BEFORE polling, which could clobber a word a slower
//    wave was still polling -> circular wait -> hang.
//  - Everything else unchanged from R5: data-is-the-flag polling (valid iff
//    no dword == 0x7FC07FC0), no flags, no per-step __syncthreads, wave-local
//    gate transpose, xg prefetch one step ahead, 2 independent batch groups.

#define B_ 32
#define T_ 512
#define H_ 512
#define M_ (B_*T_)   // 16384
#define NWG 32       // 2 groups x 16 hidden-slice WGs
#define KS 16        // K=512 / 32 per MFMA
#define HBS (32*512) // u16 per h-buffer (4 buffers)

typedef __attribute__((ext_vector_type(8))) short bf16x8;
typedef __attribute__((ext_vector_type(4))) float f32x4;
typedef __attribute__((ext_vector_type(4))) unsigned int u32x4;

__device__ inline unsigned short f2bf(float f){
  unsigned int u = __builtin_bit_cast(unsigned int, f);
  u += 0x7fffu + ((u>>16)&1u);      // round-to-nearest-even
  return (unsigned short)(u>>16);
}
__device__ inline float bf2f(unsigned short s){
  unsigned int u = ((unsigned int)s)<<16;
  return __builtin_bit_cast(float, u);
}
__device__ inline float tanh_f(float x){
  float ax = fabsf(x);
  if (ax > 12.f) return (x>0.f)?1.f:-1.f;
  float e = __expf(2.f*ax);
  float t = (e-1.f)/(e+1.f);
  return (x>=0.f)? t : -t;
}
__device__ inline float sigm(float x){ return 1.f/(1.f+__expf(-x)); }

// Device-scope (MALL coherence point) raw memory ops, bypass L1/L2 via sc1.
__device__ inline void st_u32_sc1(void* p, unsigned int v){
  asm volatile("global_store_dword %0, %1, off sc1" :: "v"(p), "v"(v) : "memory");
}
__device__ inline bf16x8 sent8(){
  union{ unsigned int u[4]; bf16x8 v; } x;
  x.u[0]=x.u[1]=x.u[2]=x.u[3]=0x7FC07FC0u; return x.v;
}

// ---------------------------------------------------------------------------
// Tiled bf16 GEMM, 128x128 tile, BK=32, 256 thr (4 waves, 2x2 of 64x64).
template<int MODE>
__global__ __launch_bounds__(256)
void gemm_k(const void* __restrict__ Ap, const float* __restrict__ Bw,
            const float* __restrict__ bias, int K,
            float* __restrict__ s1, float* __restrict__ s2, float* __restrict__ s3,
            const float* __restrict__ w1, const float* __restrict__ w2, const float* __restrict__ w3,
            unsigned short* __restrict__ outp, int ldout)
{
  __shared__ short As[128*40];
  __shared__ short Bs[128*40];
  const int tid = threadIdx.x;
  const int cb = blockIdx.x, rb = blockIdx.y;
  const int lane = tid & 63, wv = tid >> 6;
  const int vm = wv & 1, vn = wv >> 1;
  const int r = tid >> 1;
  const int c0 = (tid & 1) << 4;

  f32x4 acc[4][4];
  const f32x4 zz = {0.f,0.f,0.f,0.f};
  #pragma unroll
  for (int i=0;i<4;i++)
    #pragma unroll
    for (int j=0;j<4;j++) acc[i][j] = zz;

  union { short s[16]; bf16x8 v[2]; } tmpu;

  for (int kb = 0; kb < K; kb += 32){
    if (MODE == 0){
      const float* A = (const float*)Ap + (size_t)(rb*128 + r)*K + kb + c0;
      #pragma unroll
      for (int q=0;q<4;q++){
        float4 vv = ((const float4*)A)[q];
        tmpu.s[q*4+0]=(short)f2bf(vv.x); tmpu.s[q*4+1]=(short)f2bf(vv.y);
        tmpu.s[q*4+2]=(short)f2bf(vv.z); tmpu.s[q*4+3]=(short)f2bf(vv.w);
      }
      *(bf16x8*)&As[r*40 + c0]   = tmpu.v[0];
      *(bf16x8*)&As[r*40 + c0+8] = tmpu.v[1];
    } else {
      const unsigned short* A = (const unsigned short*)Ap + (size_t)(rb*128 + r)*K + kb + c0;
      uint4 u0 = ((const uint4*)A)[0];
      uint4 u1 = ((const uint4*)A)[1];
      *(uint4*)&As[r*40 + c0]   = u0;
      *(uint4*)&As[r*40 + c0+8] = u1;
    }
    {
      const float* Bp = Bw + (size_t)(cb*128 + r)*K + kb + c0;
      #pragma unroll
      for (int q=0;q<4;q++){
        float4 vv = ((const float4*)Bp)[q];
        tmpu.s[q*4+0]=(short)f2bf(vv.x); tmpu.s[q*4+1]=(short)f2bf(vv.y);
        tmpu.s[q*4+2]=(short)f2bf(vv.z); tmpu.s[q*4+3]=(short)f2bf(vv.w);
      }
      *(bf16x8*)&Bs[r*40 + c0]   = tmpu.v[0];
      *(bf16x8*)&Bs[r*40 + c0+8] = tmpu.v[1];
    }
    __syncthreads();
    bf16x8 af[4], bfr[4];
    const int fo = ((lane>>4)<<3);
    #pragma unroll
    for (int i=0;i<4;i++) af[i]  = *(const bf16x8*)&As[(vm*64 + i*16 + (lane&15))*40 + fo];
    #pragma unroll
    for (int i=0;i<4;i++) bfr[i] = *(const bf16x8*)&Bs[(vn*64 + i*16 + (lane&15))*40 + fo];
    #pragma unroll
    for (int mt=0;mt<4;mt++)
      #pragma unroll
      for (int nt=0;nt<4;nt++)
        acc[mt][nt] = __builtin_amdgcn_mfma_f32_16x16x32_bf16(af[mt], bfr[nt], acc[mt][nt], 0,0,0);
    __syncthreads();
  }

  const int rowbase = rb*128 + vm*64;
  const int colbase = cb*128 + vn*64;
  if (MODE == 0){
    float bv[4], w1v[4], w2v[4], w3v[4];
    #pragma unroll
    for (int nt=0;nt<4;nt++){
      int c = colbase + nt*16 + (lane&15);
      bv[nt]=bias[c]; w1v[nt]=w1[c]; w2v[nt]=w2[c]; w3v[nt]=w3[c];
    }
    #pragma unroll
    for (int mt=0;mt<4;mt++){
      #pragma unroll
      for (int rr=0;rr<4;rr++){
        float d1=0.f,d2=0.f,d3=0.f;
        #pragma unroll
        for (int nt=0;nt<4;nt++){
          float tv = tanh_f(acc[mt][nt][rr] + bv[nt]);
          d1 = fmaf(tv, w1v[nt], d1);
          d2 = fmaf(tv, w2v[nt], d2);
          d3 = fmaf(tv, w3v[nt], d3);
        }
        #pragma unroll
        for (int m=1;m<16;m<<=1){
          d1 += __shfl_xor(d1, m);
          d2 += __shfl_xor(d2, m);
          d3 += __shfl_xor(d3, m);
        }
        if ((lane & 15) == 0){
          int row = rowbase + mt*16 + ((lane>>4)<<2) + rr;
          atomicAdd(&s1[row], d1);
          atomicAdd(&s2[row], d2);
          atomicAdd(&s3[row], d3);
        }
      }
    }
  } else {
    #pragma unroll
    for (int mt=0;mt<4;mt++){
      #pragma unroll
      for (int nt=0;nt<4;nt++){
        int c = colbase + nt*16 + (lane&15);
        float bb = bias[c];
        #pragma unroll
        for (int rr=0;rr<4;rr++){
          int row = rowbase + mt*16 + ((lane>>4)<<2) + rr;
          float vv = acc[mt][nt][rr] + bb;
          if (MODE == 2) vv = fmaxf(vv, 0.f);
          outp[(size_t)row*ldout + c] = f2bf(vv);
        }
      }
    }
  }
}

// ---------------------------------------------------------------------------
__global__ __launch_bounds__(256)
void softmax_k(const float* __restrict__ sacc, float* __restrict__ sm)
{
  const int u = blockIdx.x % 21, b = blockIdx.x / 21;
  const int tid = threadIdx.x;
  __shared__ float red[4], red2[4];
  float v0, v1;
  if (u < 15){
    const int pa[15] = {0,0,0,0,0,1,1,1,1,2,2,2,3,3,4};
    const int pb[15] = {2,1,3,4,5,2,3,4,5,3,4,5,4,5,5};
    const float* A  = sacc + (size_t)(pa[u]*3+0)*M_ + b*T_;
    const float* Bq = sacc + (size_t)(pb[u]*3+1)*M_ + b*T_;
    v0 = A[tid] + Bq[tid]; v1 = A[tid+256] + Bq[tid+256];
  } else {
    const float* A = sacc + (size_t)((u-15)*3+2)*M_ + b*T_;
    v0 = A[tid]; v1 = A[tid+256];
  }
  float mx = fmaxf(v0,v1);
  #pragma unroll
  for (int d=1;d<64;d<<=1) mx = fmaxf(mx, __shfl_xor(mx,d));
  if ((tid&63)==0) red[tid>>6]=mx;
  __syncthreads();
  mx = fmaxf(fmaxf(red[0],red[1]),fmaxf(red[2],red[3]));
  float e0 = __expf(v0-mx), e1 = __expf(v1-mx);
  float s = e0+e1;
  #pragma unroll
  for (int d=1;d<64;d<<=1) s += __shfl_xor(s,d);
  if ((tid&63)==0) red2[tid>>6]=s;
  __syncthreads();
  s = red2[0]+red2[1]+red2[2]+red2[3];
  float inv = 1.f/s;
  float* o = sm + (size_t)u*M_ + b*T_;
  o[tid] = e0*inv; o[tid+256] = e1*inv;
}

// ---------------------------------------------------------------------------
// enc xg precompute: xg[row, R] = enc_b[R] + sum_{k<6} smu[k][row] * Wih[R,k].
__global__ __launch_bounds__(256)
void xgenc_k(const float* __restrict__ smu, const float* __restrict__ Wih,
             const float* __restrict__ bvec, unsigned short* __restrict__ xgo)
{
  __shared__ float Ws[6][2048];
  __shared__ float bs[2048];
  const int tid = threadIdx.x;
  for (int i = tid; i < 6*2048; i += 256){
    int R = i / 6, k = i - R*6;
    Ws[k][R] = Wih[i];
  }
  for (int i = tid; i < 2048; i += 256) bs[i] = bvec[i];
  __syncthreads();
  const int r0 = blockIdx.x * 64;
  for (int r = r0; r < r0 + 64; r++){
    float s0 = smu[0*M_ + r], s1 = smu[1*M_ + r], s2 = smu[2*M_ + r];
    float s3 = smu[3*M_ + r], s4 = smu[4*M_ + r], s5 = smu[5*M_ + r];
    unsigned short* orow = xgo + (size_t)r*2048;
    #pragma unroll
    for (int i = 0; i < 8; i++){
      int R = tid + i*256;
      float a = bs[R];
      a = fmaf(s0, Ws[0][R], a); a = fmaf(s1, Ws[1][R], a);
      a = fmaf(s2, Ws[2][R], a); a = fmaf(s3, Ws[3][R], a);
      a = fmaf(s4, Ws[4][R], a); a = fmaf(s5, Ws[5][R], a);
      orow[R] = f2bf(a);
    }
  }
}

// ---------------------------------------------------------------------------
// Seed h-buffers: buf0 = h0 data (enc: zeros, dec: dec_h0); bufs 1..3 = NaN
// sentinel. Kernel-boundary release flushes before lstm_k's sc1 reads.
__global__ __launch_bounds__(256)
void init2_k(const float* __restrict__ dh0, unsigned short* __restrict__ hbe,
             unsigned short* __restrict__ hbd)
{
  int gid = blockIdx.x*256 + threadIdx.x;  // 0..16383
  int bb = gid >> 9, j = gid & 511;
  size_t o = (size_t)bb*512 + j;
  hbe[o] = 0;
  hbd[o] = f2bf(dh0[j]);
  #pragma unroll
  for (int k=1; k<4; k++){
    hbe[(size_t)k*HBS + o] = 0x7FC0;
    hbd[(size_t)k*HBS + o] = 0x7FC0;
  }
}

// ---------------------------------------------------------------------------
// Persistent LSTM, NaN-sentinel handoff. 32 WGs x 256 thr (4 waves).
// WG w: batch group grp=w>>4 (16 batches), hidden slice ws=w&15 (32 hidden,
// 128 gate rows in VGPR fragments). Wave v owns 8 hidden units end-to-end:
// MFMA gates -> wave-local LDS transpose (no __syncthreads) -> pointwise ->
// publish. h exchange: 4 rotating buffers; readers poll data chunks of
// buf[(t-1)&3] for absence of 0x7FC07FC0 (h is finite: products of sigm/tanh,
// bf16 NaN unreachable; dword atomicity => tear-safe). AFTER the poll
// succeeds, each wave NaN-fills its own slot of buf[(t+2)&3]:
//   poll success at t => all group waves published h_{t-1} => (each publish
//   is preceded by s_waitcnt vmcnt(0)) all waves RETIRED their reads of
//   buf[(t-2)&3] == buf[(t+2)&3]  -> fill cannot clobber in-flight reads.
//   (R5 filled BEFORE the poll: a slower wave could still be polling that
//   buffer -> sentinel lands on data it needs -> circular wait -> hang.)
// Fill visibility: retired by this step's pre-publish vmcnt(0); readers poll
// buf[(t+2)&3] for h_{t+2} only at step t+3, causally after our h_t and
// h_{t+1} publishes -> fill is visible by then. Stale-register reads in the
// counted-vmcnt poll are retry-safe (stale = sentinel or identical duplicate;
// a word is stable from data-write until its NaN-refill).
__global__ __launch_bounds__(256, 1)
void lstm_k(const float* __restrict__ Whh, const unsigned short* __restrict__ xg,
            const float* __restrict__ c0v,
            unsigned short* hbuf, unsigned short* __restrict__ outbuf)
{
  const int w = blockIdx.x, tid = threadIdx.x;
  const int grp = w >> 4, ws = w & 15;
  const int lane = tid & 63, v = tid >> 6;

  // Weight fragments: wave v covers WG gate-rows rWG = v*32 + nt*16 + (lane&15);
  // rWG -> (gate = rWG&3, hidden_off = rWG>>2), R = gate*512 + ws*32 + hidden_off.
  bf16x8 bfrag[2][KS];
  {
    const int n = lane & 15;
    const int kq0 = (lane>>4)<<3;
    #pragma unroll
    for (int nt=0; nt<2; nt++){
      const int rWG = v*32 + nt*16 + n;
      const int R = (rWG & 3)*512 + ws*32 + (rWG >> 2);
      const float* Wr = Whh + (size_t)R*512 + kq0;
      for (int ks=0; ks<KS; ks++){
        union { short s[8]; bf16x8 vv; } bu;
        #pragma unroll
        for (int j=0;j<8;j++) bu.s[j] = (short)f2bf(Wr[ks*32 + j]);
        bfrag[nt][ks] = bu.vv;
      }
    }
  }
  const int m  = lane & 15;              // A-row = batch-local
  const int kq = (lane>>4) << 3;
  const int bl = lane & 15;              // gate-phase batch-local
  const int q  = lane >> 4;              // 0..3
  const int b  = grp*16 + bl;            // global batch
  const int j0 = ws*32 + v*8 + q*2;      // this lane's 2 hidden units

  float cc[2];
  cc[0] = c0v ? c0v[j0]   : 0.f;
  cc[1] = c0v ? c0v[j0+1] : 0.f;

  __shared__ float gl4[4][32*17];        // per-wave gate transpose
  float* gl = gl4[v];

  unsigned int xqC[4], xqN[4];
  {
    const unsigned short* xp = xg + ((size_t)b*512)*2048 + j0;
    #pragma unroll
    for (int g=0; g<4; g++) xqC[g] = *(const unsigned int*)(xp + g*512);
  }
  const size_t rowoff = (size_t)(grp*16 + m)*512 + kq;  // poll address base
  const size_t myoff  = (size_t)b*512 + j0;             // publish address

  const bf16x8 S8 = sent8();
  const unsigned int SW = 0x7FC07FC0u;

  for (int t = 1; t <= 512; t++){
    bf16x8 af[KS];
    #pragma unroll
    for (int ks=0; ks<KS; ks++) af[ks] = S8;   // sentinel init (kept live by "+v")

    // prefetch xg for step t+1 (plain cached loads; hide cold-HBM under poll)
    if (t < 512){
      const unsigned short* xp = xg + ((size_t)(b*512 + t))*2048 + j0;
      #pragma unroll
      for (int g=0; g<4; g++) xqN[g] = *(const unsigned int*)(xp + g*512);
    } else {
      #pragma unroll
      for (int g=0; g<4; g++) xqN[g] = 0u;
    }

    // ---- poll h_{t-1} in buf[(t-1)&3]: data IS the flag ----
    {
      const unsigned short* pb = hbuf + ((size_t)((t-1)&3))*HBS + rowoff;
      unsigned int okm;
#define PLD(i, off) asm volatile("global_load_dwordx4 %0, %1, off offset:" off " sc1" \
                                 : "+v"(af[i]) : "v"(pb) : "memory")
      do {
        PLD(0,"0");    PLD(1,"64");   PLD(2,"128");  PLD(3,"192");
        PLD(4,"256");  PLD(5,"320");  PLD(6,"384");  PLD(7,"448");
        PLD(8,"512");  PLD(9,"576");  PLD(10,"640"); PLD(11,"704");
        PLD(12,"768"); PLD(13,"832"); PLD(14,"896"); PLD(15,"960");
        // 7 outstanding allowed: under-wait is retry-safe (stale regs hold
        // sentinel or identical duplicate data; words stable until refill).
        asm volatile("s_waitcnt vmcnt(7)" ::: "memory");
        __builtin_amdgcn_sched_barrier(0);
        okm = 1u;
        #pragma unroll
        for (int ks=0; ks<KS; ks++){
          u32x4 uu = __builtin_bit_cast(u32x4, af[ks]);
          okm &= (unsigned int)(uu[0] != SW);
          okm &= (unsigned int)(uu[1] != SW);
          okm &= (unsigned int)(uu[2] != SW);
          okm &= (unsigned int)(uu[3] != SW);
        }
      } while (!__all((int)okm));
#undef PLD
    }

    // NaN-fill own slot of buf[(t+2)&3] — SAFE ONLY HERE (after poll success):
    // all group waves have published h_{t-1}, hence retired all reads of this
    // buffer as h_{t-2} data. Retired by the pre-publish vmcnt(0) below.
    st_u32_sc1(hbuf + ((size_t)((t+2)&3))*HBS + myoff, SW);

    // ---- gates = h_{t-1} @ Whh^T (MFMA, register-only) ----
    f32x4 acc0 = {0.f,0.f,0.f,0.f}, acc1 = {0.f,0.f,0.f,0.f};
    #pragma unroll
    for (int ks=0; ks<KS; ks++){
      acc0 = __builtin_amdgcn_mfma_f32_16x16x32_bf16(af[ks], bfrag[0][ks], acc0, 0,0,0);
      acc1 = __builtin_amdgcn_mfma_f32_16x16x32_bf16(af[ks], bfrag[1][ks], acc1, 0,0,0);
    }
    // ---- wave-local transpose via LDS (no __syncthreads) ----
    {
      const int qb = (lane>>4) << 2;
      #pragma unroll
      for (int rr=0; rr<4; rr++){
        gl[((lane&15))*17      + qb + rr] = acc0[rr];
        gl[(16 + (lane&15))*17 + qb + rr] = acc1[rr];
      }
    }
    asm volatile("s_waitcnt lgkmcnt(0)" ::: "memory");
    __builtin_amdgcn_sched_barrier(0);
    float g8[8];
    #pragma unroll
    for (int e=0; e<2; e++)
      #pragma unroll
      for (int gg=0; gg<4; gg++)
        g8[e*4+gg] = gl[((q*2+e)*4+gg)*17 + bl];
    // Retire everything (NaN store, xqN, duplicate poll loads) before publish.
    asm volatile("s_waitcnt vmcnt(0) lgkmcnt(0)" ::: "memory");
    __builtin_amdgcn_sched_barrier(0);

    // ---- pointwise ----
    unsigned int hv;
    {
      float hn[2];
      #pragma unroll
      for (int e=0; e<2; e++){
        float gi = g8[e*4+0] + bf2f((unsigned short)(xqC[0] >> (e*16)));
        float gf = g8[e*4+1] + bf2f((unsigned short)(xqC[1] >> (e*16)));
        float gg = g8[e*4+2] + bf2f((unsigned short)(xqC[2] >> (e*16)));
        float go = g8[e*4+3] + bf2f((unsigned short)(xqC[3] >> (e*16)));
        cc[e] = sigm(gf)*cc[e] + sigm(gi)*tanh_f(gg);
        hn[e] = sigm(go)*tanh_f(cc[e]);
      }
      hv = (unsigned int)f2bf(hn[0]) | ((unsigned int)f2bf(hn[1])<<16);
    }
    // publish (no drain, no barrier, no flag)
    st_u32_sc1(hbuf + ((size_t)(t&3))*HBS + myoff, hv);
    *(unsigned int*)(outbuf + ((size_t)(b*512 + (t-1)))*512 + j0) = hv;
    #pragma unroll
    for (int g=0; g<4; g++) xqC[g] = xqN[g];
  }
}

// ---------------------------------------------------------------------------
__global__ __launch_bounds__(256)
void ctx_k(const float* __restrict__ smatt, const unsigned short* __restrict__ enc_out,
           unsigned short* __restrict__ ctx)
{
  const int bt = blockIdx.x;
  const int b = bt >> 9, t = bt & 511;
  __shared__ float a[15];
  const int tid = threadIdx.x;
  if (tid < 15){
    int q = 15*t + tid;
    a[tid] = smatt[(size_t)(q>>9)*M_ + b*T_ + (q&511)];
  }
  __syncthreads();
  const int j0 = tid*2;
  float s0=0.f, s1=0.f;
  for (int i=0;i<15;i++){
    int tau = t - i;
    if (tau < 0) break;
    unsigned int pr = *(const unsigned int*)(enc_out + ((size_t)(b*512+tau))*512 + j0);
    float wv = a[i];
    s0 = fmaf(wv, bf2f((unsigned short)(pr & 0xffff)), s0);
    s1 = fmaf(wv, bf2f((unsigned short)(pr >> 16)), s1);
  }
  unsigned int o = (unsigned int)f2bf(s0) | ((unsigned int)f2bf(s1)<<16);
  *(unsigned int*)(ctx + (size_t)bt*512 + j0) = o;
}

// ---------------------------------------------------------------------------
__global__ __launch_bounds__(256)
void out_k(const unsigned short* __restrict__ hid, const float* __restrict__ W2,
           const float* __restrict__ b2, float* __restrict__ out)
{
  __shared__ float w2s[7*512];
  const int tid = threadIdx.x;
  for (int i = tid; i < 7*512; i += 256) w2s[i] = W2[i];
  __syncthreads();
  const int wv = tid>>6, lane = tid&63;
  const int mrow = blockIdx.x*4 + wv;
  float hv[8];
  {
    const uint4 uu = *(const uint4*)(hid + (size_t)mrow*512 + lane*8);
    const unsigned int q[4] = {uu.x, uu.y, uu.z, uu.w};
    #pragma unroll
    for (int i=0;i<4;i++){
      hv[i*2]   = bf2f((unsigned short)(q[i] & 0xffff));
      hv[i*2+1] = bf2f((unsigned short)(q[i] >> 16));
    }
  }
  float s[7];
  #pragma unroll
  for (int o=0;o<7;o++){
    float acc = 0.f;
    #pragma unroll
    for (int j=0;j<8;j++) acc = fmaf(hv[j], w2s[o*512 + lane*8 + j], acc);
    #pragma unroll
    for (int d=1; d<64; d<<=1) acc += __shfl_xor(acc, d);
    s[o] = acc;
  }
  if (lane == 0){
    #pragma unroll
    for (int o=0;o<7;o++) out[(size_t)mrow*7 + o] = s[o] + b2[o];
  }
}

// ---------------------------------------------------------------------------
// Workspace layout (needs ~136 MiB)
#define OFF_SACC   0ULL          // 18*16384*4 = 1179648
#define OFF_SM     2097152ULL    // 21*16384*4 = 1376256
#define OFF_HBUF_E 4194304ULL    // 4*32*512*2 = 131072
#define OFF_HBUF_D 4325376ULL    // 131072
#define OFF_ENCOUT 5242880ULL    // 16 MiB bf16
#define OFF_CTX    23068672ULL   // 16 MiB bf16
#define OFF_XG     41943040ULL   // 64 MiB bf16 (16384x2048), time-shared enc/dec
#define OFF_DECOUT 109051904ULL  // 16 MiB bf16
#define OFF_HID    125829120ULL  // 16 MiB bf16

extern "C" void kernel_launch(void* const* d_in, const int* in_sizes, int n_in,
                              void* d_out, int out_size, void* d_ws, size_t ws_size,
                              hipStream_t stream)
{
  const float* face  = (const float*)d_in[1];
  const float* audio = (const float*)d_in[2];
  const float* desc  = (const float*)d_in[3];
  const float* sit   = (const float*)d_in[4];
  const float* scene = (const float*)d_in[5];
  const float* text  = (const float*)d_in[6];
  const float* Wt  = (const float*)d_in[8];  const float* bt  = (const float*)d_in[9];
  const float* Wf  = (const float*)d_in[10]; const float* bfc = (const float*)d_in[11];
  const float* Wa  = (const float*)d_in[12]; const float* ba  = (const float*)d_in[13];
  const float* Wsc = (const float*)d_in[14]; const float* bsc = (const float*)d_in[15];
  const float* Wd  = (const float*)d_in[16]; const float* bd  = (const float*)d_in[17];
  const float* Wsi = (const float*)d_in[18]; const float* bsi = (const float*)d_in[19];
  const float* w_att = (const float*)d_in[20];
  const float* w_ut = (const float*)d_in[22];
  const float* w_uf = (const float*)d_in[24];
  const float* w_ua = (const float*)d_in[26];
  const float* enc_Wih = (const float*)d_in[28];
  const float* enc_Whh = (const float*)d_in[29];
  const float* enc_b   = (const float*)d_in[30];
  const float* dec_Wih = (const float*)d_in[31];
  const float* dec_Whh = (const float*)d_in[32];
  const float* dec_b   = (const float*)d_in[33];
  const float* dec_h0  = (const float*)d_in[34];
  const float* dec_c0  = (const float*)d_in[35];
  const float* W1 = (const float*)d_in[36]; const float* b1 = (const float*)d_in[37];
  const float* W2 = (const float*)d_in[38]; const float* b2 = (const float*)d_in[39];
  float* outp = (float*)d_out;

  char* ws = (char*)d_ws;
  float* sacc = (float*)(ws + OFF_SACC);
  float* sm   = (float*)(ws + OFF_SM);
  unsigned short* hbe = (unsigned short*)(ws + OFF_HBUF_E);
  unsigned short* hbd = (unsigned short*)(ws + OFF_HBUF_D);
  unsigned short* enc_out = (unsigned short*)(ws + OFF_ENCOUT);
  unsigned short* ctx = (unsigned short*)(ws + OFF_CTX);
  unsigned short* xg  = (unsigned short*)(ws + OFF_XG);
  unsigned short* dec_out = (unsigned short*)(ws + OFF_DECOUT);
  unsigned short* hid = (unsigned short*)(ws + OFF_HID);
  const float* smu = sm + 15*M_;   // uni softmaxes

  hipMemsetAsync(ws + OFF_SACC, 0, 18*M_*4, stream);

  dim3 blk(256);
  dim3 g1(4,128);
  const float* w1p = w_att; const float* w2p = w_att + 512;
  // feature order: 0=text 1=face 2=audio 3=scene 4=desc 5=sit
  gemm_k<0><<<g1, blk, 0, stream>>>(text,  Wt,  bt,  768,  sacc+0*M_,  sacc+1*M_,  sacc+2*M_,  w1p, w2p, w_ut, nullptr, 0);
  gemm_k<0><<<g1, blk, 0, stream>>>(face,  Wf,  bfc, 512,  sacc+3*M_,  sacc+4*M_,  sacc+5*M_,  w1p, w2p, w_uf, nullptr, 0);
  gemm_k<0><<<g1, blk, 0, stream>>>(audio, Wa,  ba,  128,  sacc+6*M_,  sacc+7*M_,  sacc+8*M_,  w1p, w2p, w_ua, nullptr, 0);
  gemm_k<0><<<g1, blk, 0, stream>>>(scene, Wsc, bsc, 2048, sacc+9*M_,  sacc+10*M_, sacc+11*M_, w1p, w2p, w_ut, nullptr, 0);
  gemm_k<0><<<g1, blk, 0, stream>>>(desc,  Wd,  bd,  768,  sacc+12*M_, sacc+13*M_, sacc+14*M_, w1p, w2p, w_uf, nullptr, 0);
  gemm_k<0><<<g1, blk, 0, stream>>>(sit,   Wsi, bsi, 768,  sacc+15*M_, sacc+16*M_, sacc+17*M_, w1p, w2p, w_ua, nullptr, 0);
  softmax_k<<<dim3(21*32), blk, 0, stream>>>(sacc, sm);
  xgenc_k<<<dim3(256), blk, 0, stream>>>(smu, enc_Wih, enc_b, xg);
  init2_k<<<dim3(64), blk, 0, stream>>>(dec_h0, hbe, hbd);
  lstm_k<<<dim3(NWG), dim3(256), 0, stream>>>(enc_Whh, xg, nullptr, hbe, enc_out);
  ctx_k<<<dim3(M_), blk, 0, stream>>>(sm, enc_out, ctx);
  gemm_k<1><<<dim3(16,128), blk, 0, stream>>>(ctx, dec_Wih, dec_b, 512,
      nullptr,nullptr,nullptr,nullptr,nullptr,nullptr, xg, 2048);
  lstm_k<<<dim3(NWG), dim3(256), 0, stream>>>(dec_Whh, xg, dec_c0, hbd, dec_out);
  gemm_k<2><<<dim3(4,128), blk, 0, stream>>>(dec_out, W1, b1, 512,
      nullptr,nullptr,nullptr,nullptr,nullptr,nullptr, hid, 512);
  out_k<<<dim3(M_/4), blk, 0, stream>>>(hid, W2, b2, outp);
  (void)in_sizes; (void)n_in; (void)out_size; (void)ws_size;
}

// Round 5
// 5609.915 us; speedup vs baseline: 1.5014x; 1.4233x over previous
//
#include <hip/hip_runtime.h>

// MovieNet: 6 proj GEMMs(+tanh+dot epilogue) -> 21 softmax -> enc xg (K=6 GEMM)
// -> enc LSTM (persistent) -> ctx -> dec xg GEMM -> dec LSTM (persistent) -> MLP.
// R8 == R7 (verified protocol) + bounded poll so any protocol flaw surfaces as
// a wrong answer (counters!) instead of a dead container. R7's structure:
//  - 64 WG x 128 thr; PER-WAVE flags (128 flags, one 64B line each): no
//    per-step __syncthreads. Gate transpose is wave-local (wave v writes/reads
//    gl cols v*16..v*16+15): lgkmcnt(0) suffices; each wave drains its own 4B
//    h-publish and sets its own flag (lane 0).
//  - enc xg precomputed by xgenc_k: no per-step enc staging, K uniform 512
//    (16 MFMA slices), enc/dec share one lstm_k.
//  - outbuf write AFTER the flag store, plain write-back: pre-flag vmcnt(0)
//    drains ONLY the 4B h-publish.

#define B_ 32
#define T_ 512
#define H_ 512
#define M_ (B_*T_)   // 16384
#define NWG 64       // persistent LSTM workgroups (each owns 8 hidden units)
#define KS 16        // K=512 / 32 per MFMA
#define HBS (32*512) // u16 per h-buffer (2 buffers)

typedef __attribute__((ext_vector_type(8))) short bf16x8;
typedef __attribute__((ext_vector_type(4))) float f32x4;

__device__ inline unsigned short f2bf(float f){
  unsigned int u = __builtin_bit_cast(unsigned int, f);
  u += 0x7fffu + ((u>>16)&1u);      // round-to-nearest-even
  return (unsigned short)(u>>16);
}
__device__ inline float bf2f(unsigned short s){
  unsigned int u = ((unsigned int)s)<<16;
  return __builtin_bit_cast(float, u);
}
__device__ inline float tanh_f(float x){
  float ax = fabsf(x);
  if (ax > 12.f) return (x>0.f)?1.f:-1.f;
  float e = __expf(2.f*ax);
  float t = (e-1.f)/(e+1.f);
  return (x>=0.f)? t : -t;
}
__device__ inline float sigm(float x){ return 1.f/(1.f+__expf(-x)); }

// Device-scope (MALL coherence point) raw memory ops, bypass L1/L2 via sc1.
__device__ inline void st_u32_sc1(void* p, unsigned int v){
  asm volatile("global_store_dword %0, %1, off sc1" :: "v"(p), "v"(v) : "memory");
}
__device__ inline bf16x8 ld_b128_sc1(const void* p){
  bf16x8 r;
  asm volatile("global_load_dwordx4 %0, %1, off sc1" : "=v"(r) : "v"(p));
  return r;
}

// ---------------------------------------------------------------------------
// Tiled bf16 GEMM, 128x128 tile, BK=32, 256 thr (4 waves, 2x2 of 64x64).
template<int MODE>
__global__ __launch_bounds__(256)
void gemm_k(const void* __restrict__ Ap, const float* __restrict__ Bw,
            const float* __restrict__ bias, int K,
            float* __restrict__ s1, float* __restrict__ s2, float* __restrict__ s3,
            const float* __restrict__ w1, const float* __restrict__ w2, const float* __restrict__ w3,
            unsigned short* __restrict__ outp, int ldout)
{
  __shared__ short As[128*40];
  __shared__ short Bs[128*40];
  const int tid = threadIdx.x;
  const int cb = blockIdx.x, rb = blockIdx.y;
  const int lane = tid & 63, wv = tid >> 6;
  const int vm = wv & 1, vn = wv >> 1;
  const int r = tid >> 1;
  const int c0 = (tid & 1) << 4;

  f32x4 acc[4][4];
  const f32x4 zz = {0.f,0.f,0.f,0.f};
  #pragma unroll
  for (int i=0;i<4;i++)
    #pragma unroll
    for (int j=0;j<4;j++) acc[i][j] = zz;

  union { short s[16]; bf16x8 v[2]; } tmpu;

  for (int kb = 0; kb < K; kb += 32){
    if (MODE == 0){
      const float* A = (const float*)Ap + (size_t)(rb*128 + r)*K + kb + c0;
      #pragma unroll
      for (int q=0;q<4;q++){
        float4 vv = ((const float4*)A)[q];
        tmpu.s[q*4+0]=(short)f2bf(vv.x); tmpu.s[q*4+1]=(short)f2bf(vv.y);
        tmpu.s[q*4+2]=(short)f2bf(vv.z); tmpu.s[q*4+3]=(short)f2bf(vv.w);
      }
      *(bf16x8*)&As[r*40 + c0]   = tmpu.v[0];
      *(bf16x8*)&As[r*40 + c0+8] = tmpu.v[1];
    } else {
      const unsigned short* A = (const unsigned short*)Ap + (size_t)(rb*128 + r)*K + kb + c0;
      uint4 u0 = ((const uint4*)A)[0];
      uint4 u1 = ((const uint4*)A)[1];
      *(uint4*)&As[r*40 + c0]   = u0;
      *(uint4*)&As[r*40 + c0+8] = u1;
    }
    {
      const float* Bp = Bw + (size_t)(cb*128 + r)*K + kb + c0;
      #pragma unroll
      for (int q=0;q<4;q++){
        float4 vv = ((const float4*)Bp)[q];
        tmpu.s[q*4+0]=(short)f2bf(vv.x); tmpu.s[q*4+1]=(short)f2bf(vv.y);
        tmpu.s[q*4+2]=(short)f2bf(vv.z); tmpu.s[q*4+3]=(short)f2bf(vv.w);
      }
      *(bf16x8*)&Bs[r*40 + c0]   = tmpu.v[0];
      *(bf16x8*)&Bs[r*40 + c0+8] = tmpu.v[1];
    }
    __syncthreads();
    bf16x8 af[4], bfr[4];
    const int fo = ((lane>>4)<<3);
    #pragma unroll
    for (int i=0;i<4;i++) af[i]  = *(const bf16x8*)&As[(vm*64 + i*16 + (lane&15))*40 + fo];
    #pragma unroll
    for (int i=0;i<4;i++) bfr[i] = *(const bf16x8*)&Bs[(vn*64 + i*16 + (lane&15))*40 + fo];
    #pragma unroll
    for (int mt=0;mt<4;mt++)
      #pragma unroll
      for (int nt=0;nt<4;nt++)
        acc[mt][nt] = __builtin_amdgcn_mfma_f32_16x16x32_bf16(af[mt], bfr[nt], acc[mt][nt], 0,0,0);
    __syncthreads();
  }

  const int rowbase = rb*128 + vm*64;
  const int colbase = cb*128 + vn*64;
  if (MODE == 0){
    float bv[4], w1v[4], w2v[4], w3v[4];
    #pragma unroll
    for (int nt=0;nt<4;nt++){
      int c = colbase + nt*16 + (lane&15);
      bv[nt]=bias[c]; w1v[nt]=w1[c]; w2v[nt]=w2[c]; w3v[nt]=w3[c];
    }
    #pragma unroll
    for (int mt=0;mt<4;mt++){
      #pragma unroll
      for (int rr=0;rr<4;rr++){
        float d1=0.f,d2=0.f,d3=0.f;
        #pragma unroll
        for (int nt=0;nt<4;nt++){
          float tv = tanh_f(acc[mt][nt][rr] + bv[nt]);
          d1 = fmaf(tv, w1v[nt], d1);
          d2 = fmaf(tv, w2v[nt], d2);
          d3 = fmaf(tv, w3v[nt], d3);
        }
        #pragma unroll
        for (int m=1;m<16;m<<=1){
          d1 += __shfl_xor(d1, m);
          d2 += __shfl_xor(d2, m);
          d3 += __shfl_xor(d3, m);
        }
        if ((lane & 15) == 0){
          int row = rowbase + mt*16 + ((lane>>4)<<2) + rr;
          atomicAdd(&s1[row], d1);
          atomicAdd(&s2[row], d2);
          atomicAdd(&s3[row], d3);
        }
      }
    }
  } else {
    #pragma unroll
    for (int mt=0;mt<4;mt++){
      #pragma unroll
      for (int nt=0;nt<4;nt++){
        int c = colbase + nt*16 + (lane&15);
        float bb = bias[c];
        #pragma unroll
        for (int rr=0;rr<4;rr++){
          int row = rowbase + mt*16 + ((lane>>4)<<2) + rr;
          float vv = acc[mt][nt][rr] + bb;
          if (MODE == 2) vv = fmaxf(vv, 0.f);
          outp[(size_t)row*ldout + c] = f2bf(vv);
        }
      }
    }
  }
}

// ---------------------------------------------------------------------------
__global__ __launch_bounds__(256)
void softmax_k(const float* __restrict__ sacc, float* __restrict__ sm)
{
  const int u = blockIdx.x % 21, b = blockIdx.x / 21;
  const int tid = threadIdx.x;
  __shared__ float red[4], red2[4];
  float v0, v1;
  if (u < 15){
    const int pa[15] = {0,0,0,0,0,1,1,1,1,2,2,2,3,3,4};
    const int pb[15] = {2,1,3,4,5,2,3,4,5,3,4,5,4,5,5};
    const float* A  = sacc + (size_t)(pa[u]*3+0)*M_ + b*T_;
    const float* Bq = sacc + (size_t)(pb[u]*3+1)*M_ + b*T_;
    v0 = A[tid] + Bq[tid]; v1 = A[tid+256] + Bq[tid+256];
  } else {
    const float* A = sacc + (size_t)((u-15)*3+2)*M_ + b*T_;
    v0 = A[tid]; v1 = A[tid+256];
  }
  float mx = fmaxf(v0,v1);
  #pragma unroll
  for (int d=1;d<64;d<<=1) mx = fmaxf(mx, __shfl_xor(mx,d));
  if ((tid&63)==0) red[tid>>6]=mx;
  __syncthreads();
  mx = fmaxf(fmaxf(red[0],red[1]),fmaxf(red[2],red[3]));
  float e0 = __expf(v0-mx), e1 = __expf(v1-mx);
  float s = e0+e1;
  #pragma unroll
  for (int d=1;d<64;d<<=1) s += __shfl_xor(s,d);
  if ((tid&63)==0) red2[tid>>6]=s;
  __syncthreads();
  s = red2[0]+red2[1]+red2[2]+red2[3];
  float inv = 1.f/s;
  float* o = sm + (size_t)u*M_ + b*T_;
  o[tid] = e0*inv; o[tid+256] = e1*inv;
}

// ---------------------------------------------------------------------------
// enc xg precompute: xg[row, R] = enc_b[R] + sum_{k<6} smu[k][row] * Wih[R,k].
__global__ __launch_bounds__(256)
void xgenc_k(const float* __restrict__ smu, const float* __restrict__ Wih,
             const float* __restrict__ bvec, unsigned short* __restrict__ xgo)
{
  __shared__ float Ws[6][2048];
  __shared__ float bs[2048];
  const int tid = threadIdx.x;
  for (int i = tid; i < 6*2048; i += 256){
    int R = i / 6, k = i - R*6;
    Ws[k][R] = Wih[i];
  }
  for (int i = tid; i < 2048; i += 256) bs[i] = bvec[i];
  __syncthreads();
  const int r0 = blockIdx.x * 64;
  for (int r = r0; r < r0 + 64; r++){
    float s0 = smu[0*M_ + r], s1 = smu[1*M_ + r], s2 = smu[2*M_ + r];
    float s3 = smu[3*M_ + r], s4 = smu[4*M_ + r], s5 = smu[5*M_ + r];
    unsigned short* orow = xgo + (size_t)r*2048;
    #pragma unroll
    for (int i = 0; i < 8; i++){
      int R = tid + i*256;
      float a = bs[R];
      a = fmaf(s0, Ws[0][R], a); a = fmaf(s1, Ws[1][R], a);
      a = fmaf(s2, Ws[2][R], a); a = fmaf(s3, Ws[3][R], a);
      a = fmaf(s4, Ws[4][R], a); a = fmaf(s5, Ws[5][R], a);
      orow[R] = f2bf(a);
    }
  }
}

// ---------------------------------------------------------------------------
// Seed h-buffers buf0: enc zeros, dec dec_h0. Kernel-boundary release
// flushes to MALL before lstm_k's sc1 reads.
__global__ __launch_bounds__(256)
void init2_k(const float* __restrict__ dh0, unsigned short* __restrict__ hbe,
             unsigned short* __restrict__ hbd)
{
  int gid = blockIdx.x*256 + threadIdx.x;  // 0..16383
  int bb = gid >> 9, j = gid & 511;
  size_t o = (size_t)bb*512 + j;
  hbe[o] = 0;
  hbd[o] = f2bf(dh0[j]);
}

// ---------------------------------------------------------------------------
// Persistent LSTM. 64 WGs x 128 thr (2 waves). WG w owns hidden [w*8, w*8+8);
// wave v owns hidden w*8+v*4..+3 END-TO-END (gates, transpose, pointwise,
// publish) -> no per-step __syncthreads anywhere.
// Handoff: double-buffered global hbuf + PER-WAVE flags (128 flags, one 64B
// line each). Protocol per wave per step t:
//   poll all 128 wave-flags >= t-1 (2 sc1 loads/lane over 128 lines)
//   load h rows (sc1), vmcnt(0)  [retires our buf[(t-1)&1] reads]
//   MFMA -> wave-local LDS transpose (lgkmcnt(0) only) -> pointwise
//   publish h slice (st_u32 sc1) -> vmcnt(0) -> lane0: flag[wid] = t
//   outbuf plain store + next-step xg loads (AFTER flag: off critical path)
// Buffer-reuse safety: flag=t implies that wave's reads of buf[(t-1)&1]
// retired (its pre-MFMA vmcnt(0)); writers touch buf[(t+1)&1]==buf[(t-1)&1]
// only after polling all flags >= t.
// Poll is BOUNDED (~4M spins ~ >100ms): a protocol flaw surfaces as a wrong
// answer (passed=false + counters) instead of a hung container.
__global__ __launch_bounds__(128, 1)
void lstm_k(const float* __restrict__ Whh, const unsigned short* __restrict__ xg,
            const float* __restrict__ c0v,
            unsigned short* hbuf, int* flags, unsigned short* __restrict__ outbuf)
{
  const int w = blockIdx.x, tid = threadIdx.x;
  const int lane = tid & 63, v = tid >> 6;
  const int wid = w*2 + v;               // wave id 0..127

  // Weight fragments: lane n=lane&15 -> gate row R = (n&3)*512 + w*8 + v*4 + (n>>2)
  bf16x8 bfrag[KS];
  {
    const int n = lane & 15;
    const int kq0 = (lane>>4)<<3;
    const int R = (n&3)*512 + w*8 + v*4 + (n>>2);
    const float* Wr = Whh + (size_t)R*512 + kq0;
    for (int ks=0; ks<KS; ks++){
      union { short s[8]; bf16x8 vv; } bu;
      #pragma unroll
      for (int j=0;j<8;j++) bu.s[j] = (short)f2bf(Wr[ks*32 + j]);
      bfrag[ks] = bu.vv;
    }
  }
  const int m  = lane & 15;              // A-row (batch / batch+16)
  const int kq = (lane>>4) << 3;         // k-chunk within 32 (u16)
  const int b  = tid & 31, u = tid >> 5; // pointwise: batch, hidden pair idx
  const int j0 = w*8 + u*2;              // this thread's 2 hidden units

  float c0 = c0v ? c0v[j0]   : 0.f;
  float c1 = c0v ? c0v[j0+1] : 0.f;

  __shared__ float gl[32*33];            // gate transpose; cols wave-disjoint

  for (int t = 1; t <= 512; t++){
    // xg for this step (issued before poll; retired by poll's vmcnt(0))
    unsigned int xw[4];
    {
      const unsigned short* xp = xg + ((size_t)(b*512 + (t-1)))*2048 + j0;
      #pragma unroll
      for (int g=0; g<4; g++) xw[g] = *(const unsigned int*)(xp + g*512);
    }
    // ---- poll: all 128 wave-flags >= t-1 (each flag on its own line) ----
    {
      const int want = t-1;
      const int* fa = flags + (size_t)lane*16;
      const int* fb = flags + (size_t)(64+lane)*16;
      int f0, f1, spin = 0;
      do {
        asm volatile("global_load_dword %0, %2, off sc1\n\t"
                     "global_load_dword %1, %3, off sc1\n\t"
                     "s_waitcnt vmcnt(0)"
                     : "=v"(f0), "=v"(f1) : "v"(fa), "v"(fb) : "memory");
      } while (!__all((f0 >= want) && (f1 >= want)) && ++spin < (1<<22));
    }
    // ---- load h_{t-1}, gate MFMA ----
    const unsigned short* hb = hbuf + ((size_t)((t-1)&1))*HBS;
    f32x4 acc0 = {0.f,0.f,0.f,0.f}, acc1 = {0.f,0.f,0.f,0.f};
    {
      bf16x8 af0[KS], af1[KS];
      #pragma unroll
      for (int ks=0; ks<KS; ks++){
        af0[ks] = ld_b128_sc1(hb + (size_t)m*512 + ks*32 + kq);
        af1[ks] = ld_b128_sc1(hb + (size_t)(m+16)*512 + ks*32 + kq);
      }
      asm volatile("s_waitcnt vmcnt(0)" ::: "memory");
      __builtin_amdgcn_sched_barrier(0);
      #pragma unroll
      for (int ks=0; ks<KS; ks++){   // register barrier: pin MFMA after waitcnt
        asm volatile("" : "+v"(af0[ks]));
        asm volatile("" : "+v"(af1[ks]));
      }
      #pragma unroll
      for (int ks=0; ks<KS; ks++){
        acc0 = __builtin_amdgcn_mfma_f32_16x16x32_bf16(af0[ks], bfrag[ks], acc0, 0,0,0);
        acc1 = __builtin_amdgcn_mfma_f32_16x16x32_bf16(af1[ks], bfrag[ks], acc1, 0,0,0);
      }
    }
    // ---- wave-local gate transpose (no __syncthreads) ----
    {
      const int col = v*16 + (lane&15);
      const int qb = (lane>>4)<<2;
      #pragma unroll
      for (int rr=0;rr<4;rr++) gl[col*33 + qb + rr] = acc0[rr];
      #pragma unroll
      for (int rr=0;rr<4;rr++) gl[col*33 + 16 + qb + rr] = acc1[rr];
    }
    asm volatile("s_waitcnt lgkmcnt(0)" ::: "memory");
    __builtin_amdgcn_sched_barrier(0);
    // ---- pointwise (reads only this wave's gl cols) ----
    unsigned int hv;
    {
      float hn[2];
      #pragma unroll
      for (int e=0;e<2;e++){
        const int jl = u*2 + e;
        const int colb = (jl>>2)*16 + (jl&3)*4;
        float gi = gl[(colb+0)*33 + b] + bf2f((unsigned short)(xw[0] >> (e*16)));
        float gf = gl[(colb+1)*33 + b] + bf2f((unsigned short)(xw[1] >> (e*16)));
        float gg = gl[(colb+2)*33 + b] + bf2f((unsigned short)(xw[2] >> (e*16)));
        float go = gl[(colb+3)*33 + b] + bf2f((unsigned short)(xw[3] >> (e*16)));
        float& cc = e ? c1 : c0;
        cc = sigm(gf)*cc + sigm(gi)*tanh_f(gg);
        hn[e] = sigm(go)*tanh_f(cc);
      }
      hv = (unsigned int)f2bf(hn[0]) | ((unsigned int)f2bf(hn[1])<<16);
    }
    // ---- publish h slice, drain ONLY it, set own wave flag ----
    st_u32_sc1(hbuf + ((size_t)(t&1))*HBS + (size_t)b*512 + j0, hv);
    asm volatile("s_waitcnt vmcnt(0)" ::: "memory");
    if (lane == 0) st_u32_sc1(&flags[(size_t)wid*16], (unsigned int)t);
    // off-critical-path: outbuf (plain write-back; flushed by kernel end)
    *(unsigned int*)(outbuf + ((size_t)(b*512 + (t-1)))*512 + j0) = hv;
  }
}

// ---------------------------------------------------------------------------
__global__ __launch_bounds__(256)
void ctx_k(const float* __restrict__ smatt, const unsigned short* __restrict__ enc_out,
           unsigned short* __restrict__ ctx)
{
  const int bt = blockIdx.x;
  const int b = bt >> 9, t = bt & 511;
  __shared__ float a[15];
  const int tid = threadIdx.x;
  if (tid < 15){
    int q = 15*t + tid;
    a[tid] = smatt[(size_t)(q>>9)*M_ + b*T_ + (q&511)];
  }
  __syncthreads();
  const int j0 = tid*2;
  float s0=0.f, s1=0.f;
  for (int i=0;i<15;i++){
    int tau = t - i;
    if (tau < 0) break;
    unsigned int pr = *(const unsigned int*)(enc_out + ((size_t)(b*512+tau))*512 + j0);
    float wv = a[i];
    s0 = fmaf(wv, bf2f((unsigned short)(pr & 0xffff)), s0);
    s1 = fmaf(wv, bf2f((unsigned short)(pr >> 16)), s1);
  }
  unsigned int o = (unsigned int)f2bf(s0) | ((unsigned int)f2bf(s1)<<16);
  *(unsigned int*)(ctx + (size_t)bt*512 + j0) = o;
}

// ---------------------------------------------------------------------------
__global__ __launch_bounds__(256)
void out_k(const unsigned short* __restrict__ hid, const float* __restrict__ W2,
           const float* __restrict__ b2, float* __restrict__ out)
{
  __shared__ float w2s[7*512];
  const int tid = threadIdx.x;
  for (int i = tid; i < 7*512; i += 256) w2s[i] = W2[i];
  __syncthreads();
  const int wv = tid>>6, lane = tid&63;
  const int mrow = blockIdx.x*4 + wv;
  float hv[8];
  {
    const uint4 uu = *(const uint4*)(hid + (size_t)mrow*512 + lane*8);
    const unsigned int q[4] = {uu.x, uu.y, uu.z, uu.w};
    #pragma unroll
    for (int i=0;i<4;i++){
      hv[i*2]   = bf2f((unsigned short)(q[i] & 0xffff));
      hv[i*2+1] = bf2f((unsigned short)(q[i] >> 16));
    }
  }
  float s[7];
  #pragma unroll
  for (int o=0;o<7;o++){
    float acc = 0.f;
    #pragma unroll
    for (int j=0;j<8;j++) acc = fmaf(hv[j], w2s[o*512 + lane*8 + j], acc);
    #pragma unroll
    for (int d=1; d<64; d<<=1) acc += __shfl_xor(acc, d);
    s[o] = acc;
  }
  if (lane == 0){
    #pragma unroll
    for (int o=0;o<7;o++) out[(size_t)mrow*7 + o] = s[o] + b2[o];
  }
}

// ---------------------------------------------------------------------------
// Workspace layout (needs ~136 MiB)
#define OFF_SACC   0ULL          // 18*16384*4 = 1179648
#define OFF_SM     2097152ULL    // 21*16384*4 = 1376256
#define OFF_FLAGS  3670016ULL    // enc:+0 (8 KiB), dec:+8192 (8 KiB)
#define OFF_HBUF_E 4194304ULL    // 2*32*512*2 = 65536
#define OFF_HBUF_D 4325376ULL    // 65536
#define OFF_ENCOUT 5242880ULL    // 16 MiB bf16
#define OFF_CTX    23068672ULL   // 16 MiB bf16
#define OFF_XG     41943040ULL   // 64 MiB bf16 (16384x2048), time-shared enc/dec
#define OFF_DECOUT 109051904ULL  // 16 MiB bf16
#define OFF_HID    125829120ULL  // 16 MiB bf16

extern "C" void kernel_launch(void* const* d_in, const int* in_sizes, int n_in,
                              void* d_out, int out_size, void* d_ws, size_t ws_size,
                              hipStream_t stream)
{
  const float* face  = (const float*)d_in[1];
  const float* audio = (const float*)d_in[2];
  const float* desc  = (const float*)d_in[3];
  const float* sit   = (const float*)d_in[4];
  const float* scene = (const float*)d_in[5];
  const float* text  = (const float*)d_in[6];
  const float* Wt  = (const float*)d_in[8];  const float* bt  = (const float*)d_in[9];
  const float* Wf  = (const float*)d_in[10]; const float* bfc = (const float*)d_in[11];
  const float* Wa  = (const float*)d_in[12]; const float* ba  = (const float*)d_in[13];
  const float* Wsc = (const float*)d_in[14]; const float* bsc = (const float*)d_in[15];
  const float* Wd  = (const float*)d_in[16]; const float* bd  = (const float*)d_in[17];
  const float* Wsi = (const float*)d_in[18]; const float* bsi = (const float*)d_in[19];
  const float* w_att = (const float*)d_in[20];
  const float* w_ut = (const float*)d_in[22];
  const float* w_uf = (const float*)d_in[24];
  const float* w_ua = (const float*)d_in[26];
  const float* enc_Wih = (const float*)d_in[28];
  const float* enc_Whh = (const float*)d_in[29];
  const float* enc_b   = (const float*)d_in[30];
  const float* dec_Wih = (const float*)d_in[31];
  const float* dec_Whh = (const float*)d_in[32];
  const float* dec_b   = (const float*)d_in[33];
  const float* dec_h0  = (const float*)d_in[34];
  const float* dec_c0  = (const float*)d_in[35];
  const float* W1 = (const float*)d_in[36]; const float* b1 = (const float*)d_in[37];
  const float* W2 = (const float*)d_in[38]; const float* b2 = (const float*)d_in[39];
  float* outp = (float*)d_out;

  char* ws = (char*)d_ws;
  float* sacc = (float*)(ws + OFF_SACC);
  float* sm   = (float*)(ws + OFF_SM);
  int* flagsE = (int*)(ws + OFF_FLAGS);
  int* flagsD = (int*)(ws + OFF_FLAGS + 8192);
  unsigned short* hbe = (unsigned short*)(ws + OFF_HBUF_E);
  unsigned short* hbd = (unsigned short*)(ws + OFF_HBUF_D);
  unsigned short* enc_out = (unsigned short*)(ws + OFF_ENCOUT);
  unsigned short* ctx = (unsigned short*)(ws + OFF_CTX);
  unsigned short* xg  = (unsigned short*)(ws + OFF_XG);
  unsigned short* dec_out = (unsigned short*)(ws + OFF_DECOUT);
  unsigned short* hid = (unsigned short*)(ws + OFF_HID);
  const float* smu = sm + 15*M_;   // uni softmaxes

  hipMemsetAsync(ws + OFF_SACC, 0, 18*M_*4, stream);
  hipMemsetAsync(ws + OFF_FLAGS, 0, 16384, stream);

  dim3 blk(256);
  dim3 g1(4,128);
  const float* w1p = w_att; const float* w2p = w_att + 512;
  // feature order: 0=text 1=face 2=audio 3=scene 4=desc 5=sit
  gemm_k<0><<<g1, blk, 0, stream>>>(text,  Wt,  bt,  768,  sacc+0*M_,  sacc+1*M_,  sacc+2*M_,  w1p, w2p, w_ut, nullptr, 0);
  gemm_k<0><<<g1, blk, 0, stream>>>(face,  Wf,  bfc, 512,  sacc+3*M_,  sacc+4*M_,  sacc+5*M_,  w1p, w2p, w_uf, nullptr, 0);
  gemm_k<0><<<g1, blk, 0, stream>>>(audio, Wa,  ba,  128,  sacc+6*M_,  sacc+7*M_,  sacc+8*M_,  w1p, w2p, w_ua, nullptr, 0);
  gemm_k<0><<<g1, blk, 0, stream>>>(scene, Wsc, bsc, 2048, sacc+9*M_,  sacc+10*M_, sacc+11*M_, w1p, w2p, w_ut, nullptr, 0);
  gemm_k<0><<<g1, blk, 0, stream>>>(desc,  Wd,  bd,  768,  sacc+12*M_, sacc+13*M_, sacc+14*M_, w1p, w2p, w_uf, nullptr, 0);
  gemm_k<0><<<g1, blk, 0, stream>>>(sit,   Wsi, bsi, 768,  sacc+15*M_, sacc+16*M_, sacc+17*M_, w1p, w2p, w_ua, nullptr, 0);
  softmax_k<<<dim3(21*32), blk, 0, stream>>>(sacc, sm);
  xgenc_k<<<dim3(256), blk, 0, stream>>>(smu, enc_Wih, enc_b, xg);
  init2_k<<<dim3(64), blk, 0, stream>>>(dec_h0, hbe, hbd);
  lstm_k<<<dim3(NWG), dim3(128), 0, stream>>>(enc_Whh, xg, nullptr, hbe, flagsE, enc_out);
  ctx_k<<<dim3(M_), blk, 0, stream>>>(sm, enc_out, ctx);
  gemm_k<1><<<dim3(16,128), blk, 0, stream>>>(ctx, dec_Wih, dec_b, 512,
      nullptr,nullptr,nullptr,nullptr,nullptr,nullptr, xg, 2048);
  lstm_k<<<dim3(NWG), dim3(128), 0, stream>>>(dec_Whh, xg, dec_c0, hbd, flagsD, dec_out);
  gemm_k<2><<<dim3(4,128), blk, 0, stream>>>(dec_out, W1, b1, 512,
      nullptr,nullptr,nullptr,nullptr,nullptr,nullptr, hid, 512);
  out_k<<<dim3(M_/4), blk, 0, stream>>>(hid, W2, b2, outp);
  (void)in_sizes; (void)n_in; (void)out_size; (void)ws_size;
}